// Round 8
// baseline (499.182 us; speedup 1.0000x reference)
//
#include <hip/hip_runtime.h>
#include <cstdint>
#include <cstddef>

typedef unsigned short u16;
typedef short bf16x8 __attribute__((ext_vector_type(8)));
typedef float f32x4 __attribute__((ext_vector_type(4)));
typedef unsigned short u16x8 __attribute__((ext_vector_type(8)));

#define DEVINL __device__ __forceinline__

DEVINL u16 f2bf(float f) {
  union { float f; unsigned u; } v; v.f = f;
  unsigned r = v.u + 0x7FFFu + ((v.u >> 16) & 1u);
  return (u16)(r >> 16);
}
DEVINL float bf2f(u16 h) {
  union { unsigned u; float f; } v; v.u = ((unsigned)h) << 16;
  return v.f;
}
DEVINL float gelu_exact(float x) {
  return 0.5f * x * (1.0f + erff(x * 0.70710678118654752f));
}
DEVINL void gload_lds16(const void* g, void* l) {
  __builtin_amdgcn_global_load_lds(
      (const __attribute__((address_space(1))) void*)g,
      (__attribute__((address_space(3))) void*)l, 16, 0, 0);
}
DEVINL bf16x8 ld_frag(const u16* p) {
  return *reinterpret_cast<const bf16x8*>(p);
}

// ---------------------------------------------------------------- convert x
__global__ __launch_bounds__(256) void conv_f32_bf16(
    const float* __restrict__ src, u16* __restrict__ dst, int n4) {
  int i = blockIdx.x * 256 + threadIdx.x;
  int stride = gridDim.x * 256;
  for (; i < n4; i += stride) {
    float4 v = reinterpret_cast<const float4*>(src)[i];
    ushort4 o;
    o.x = f2bf(v.x); o.y = f2bf(v.y); o.z = f2bf(v.z); o.w = f2bf(v.w);
    reinterpret_cast<ushort4*>(dst)[i] = o;
  }
}

// ------------------------------------------------- fused weight converts
struct ConvTab {
  const float* src[8];
  u16* dst[8];
  int bstart[8];
};
__global__ __launch_bounds__(256) void conv_w_fused(ConvTab t) {
  int blk = blockIdx.x;
  int seg = 0;
#pragma unroll
  for (int i = 1; i < 8; ++i)
    if (blk >= t.bstart[i]) seg = i;
  const float* src = t.src[seg];
  u16* dst = t.dst[seg];
  int base = (blk - t.bstart[seg]) * 1024 + threadIdx.x;
#pragma unroll
  for (int k = 0; k < 4; ++k) {
    int i = base + k * 256;
    float4 v = reinterpret_cast<const float4*>(src)[i];
    ushort4 o;
    o.x = f2bf(v.x); o.y = f2bf(v.y); o.z = f2bf(v.z); o.w = f2bf(v.w);
    reinterpret_cast<ushort4*>(dst)[i] = o;
  }
}

// ---------------------------------------------------------------- GEMM (B^T)
struct EpiSeg {
  const float* bias;
  void* dst;
  int stride;
  int col_start;
  int do_gelu;
};
struct EpiTable { EpiSeg s[4]; int nseg; };

template <int F32OUT>
__global__ __launch_bounds__(256) void gemm_bt(
    const u16* __restrict__ A, const u16* __restrict__ W, int K, EpiTable et) {
  __shared__ u16 As[128 * 32];
  __shared__ u16 Bs[128 * 32];
  const int tid = threadIdx.x;
  const int lane = tid & 63;
  const int wv = tid >> 6;
  const int g = lane >> 4;
  const int c = lane & 15;
  const int wr = (wv >> 1) * 64;
  const int wc = (wv & 1) * 64;

  int bx = blockIdx.x, by = blockIdx.y;
  {
    int nwg = gridDim.x * gridDim.y;
    if ((nwg & 7) == 0) {
      int lid = by * gridDim.x + bx;
      int qq = nwg >> 3;
      int swz = (lid & 7) * qq + (lid >> 3);
      bx = swz % gridDim.x;
      by = swz / gridDim.x;
    }
  }
  const long long rowBase = (long long)bx * 128;
  const long long colBase = (long long)by * 128;

  f32x4 acc[4][4];
#pragma unroll
  for (int m = 0; m < 4; ++m)
#pragma unroll
    for (int n = 0; n < 4; ++n) acc[m][n] = {0.f, 0.f, 0.f, 0.f};

  const int r0 = tid >> 2, sp0 = tid & 3;
  const int scol = (sp0 ^ ((r0 >> 1) & 3)) * 8;
  const u16* Ag = A + (rowBase + r0) * K + scol;
  const u16* Wg = W + (colBase + r0) * K + scol;
  u16* Al0 = As + tid * 8;
  u16* Al1 = As + (256 + tid) * 8;
  u16* Bl0 = Bs + tid * 8;
  u16* Bl1 = Bs + (256 + tid) * 8;
  const long long skip = 64LL * K;

  int aoff[4], boff[4];
#pragma unroll
  for (int m = 0; m < 4; ++m) {
    int row = wr + m * 16 + c;
    aoff[m] = row * 32 + ((g ^ ((row >> 1) & 3)) * 8);
    int rowb = wc + m * 16 + c;
    boff[m] = rowb * 32 + ((g ^ ((rowb >> 1) & 3)) * 8);
  }

  const int nk = K >> 5;
  for (int kt = 0; kt < nk; ++kt) {
    const int k0 = kt * 32;
    gload_lds16(Ag + k0, Al0);
    gload_lds16(Ag + skip + k0, Al1);
    gload_lds16(Wg + k0, Bl0);
    gload_lds16(Wg + skip + k0, Bl1);
    __syncthreads();
    bf16x8 a[4], b[4];
#pragma unroll
    for (int m = 0; m < 4; ++m) a[m] = ld_frag(&As[aoff[m]]);
#pragma unroll
    for (int n = 0; n < 4; ++n) b[n] = ld_frag(&Bs[boff[n]]);
#pragma unroll
    for (int m = 0; m < 4; ++m)
#pragma unroll
      for (int n = 0; n < 4; ++n)
        acc[m][n] = __builtin_amdgcn_mfma_f32_16x16x32_bf16(a[m], b[n], acc[m][n], 0, 0, 0);
    __syncthreads();
  }

  EpiSeg e = et.s[0];
#pragma unroll
  for (int i = 1; i < 4; ++i)
    if (i < et.nseg && (int)colBase >= et.s[i].col_start) e = et.s[i];

#pragma unroll
  for (int m = 0; m < 4; ++m) {
#pragma unroll
    for (int n = 0; n < 4; ++n) {
      int col = (int)colBase + wc + n * 16 + c;
      int dcol = col - e.col_start;
      float bias = e.bias[dcol];
#pragma unroll
      for (int r = 0; r < 4; ++r) {
        long long row = rowBase + wr + m * 16 + g * 4 + r;
        float v = acc[m][n][r] + bias;
        if (e.do_gelu) v = gelu_exact(v);
        if (F32OUT)
          ((float*)e.dst)[row * e.stride + dcol] = v;
        else
          ((u16*)e.dst)[row * e.stride + dcol] = f2bf(v);
      }
    }
  }
}

// ---------------------------------------------------------------- RoPE + gelu
__global__ __launch_bounds__(256) void rope_gelu_k(
    const u16* __restrict__ cqr, const u16* __restrict__ ckr,
    u16* __restrict__ Qb, u16* __restrict__ Kb) {
  int idx = blockIdx.x * 256 + threadIdx.x;
  int row = idx >> 6, j = idx & 63;
  int s = row & 2047;
  float invf = exp2f(-(float)j * (13.287712379549449f / 64.f));
  float th = (float)s * invf;
  float sn, cs;
  sincosf(th, &sn, &cs);
  long long r128 = (long long)row * 128;
  float q1 = bf2f(cqr[r128 + j]), q2 = bf2f(cqr[r128 + 64 + j]);
  float k1 = bf2f(ckr[r128 + j]), k2 = bf2f(ckr[r128 + 64 + j]);
  float qo1 = q1 * cs - q2 * sn, qo2 = q2 * cs + q1 * sn;
  float ko1 = k1 * cs - k2 * sn, ko2 = k2 * cs + k1 * sn;
  long long rb = (long long)row * 512;
  Qb[rb + 384 + j] = f2bf(gelu_exact(qo1));
  Qb[rb + 448 + j] = f2bf(gelu_exact(qo2));
  Kb[rb + 384 + j] = f2bf(gelu_exact(ko1));
  Kb[rb + 448 + j] = f2bf(gelu_exact(ko2));
}

// ---------------------------------------------------------------- attention
// Diagonal-paired causal flash attention, KVB=128.
// Block = 4 waves, q-tiles p and 31-p (64 rows each; wave owns 16 rows/tile).
// Per block: exactly 17 kv-iterations of 128 kv.
// Barriers: 3 per 128-kv iteration (was 3 per 64 kv).
// Ps is wave-private (each wave writes+reads only rows wv*16..wv*16+15), so
// PV follows softmax with no barrier and one Ps buffer serves both tiles.
__global__ __launch_bounds__(256) void attn_fwd(
    const u16* __restrict__ Q, const u16* __restrict__ Kin,
    const u16* __restrict__ V, u16* __restrict__ O) {
  const int p = blockIdx.x;        // pair id 0..15
  const int bh = blockIdx.y;
  const int b = bh >> 3, h = bh & 7;
  const int tid = threadIdx.x, lane = tid & 63, wv = tid >> 6;
  const int g = lane >> 4, c = lane & 15;

  __shared__ u16 Ks[128 * 64];     // [kv][d-slot swizzled] 16KB
  __shared__ u16 Vt[64 * 136];     // [d][kv] transposed, padded 17.4KB
  __shared__ u16 Ps[64 * 136];     // [q][kv], padded, wave-private rows 17.4KB

  const long long rowB = (long long)b * 2048;
  const int qb[2] = { p * 64, (31 - p) * 64 };
  const u16* Kp = Kin + rowB * 512 + h * 64;
  const u16* Vp = V + rowB * 512 + h * 64;

  // Q fragments (A-operand: lane holds Q[row=c][k=g*8..+7])
  bf16x8 qa[2][2];
#pragma unroll
  for (int tl = 0; tl < 2; ++tl) {
    const u16* Qp = Q + (rowB + qb[tl] + wv * 16 + c) * 512 + h * 64;
#pragma unroll
    for (int kc = 0; kc < 2; ++kc)
      qa[tl][kc] = ld_frag(Qp + kc * 32 + g * 8);
  }

  f32x4 o[2][4];
  float m_[2][4], l_[2][4];
#pragma unroll
  for (int tl = 0; tl < 2; ++tl) {
#pragma unroll
    for (int nf = 0; nf < 4; ++nf) o[tl][nf] = {0.f, 0.f, 0.f, 0.f};
#pragma unroll
    for (int r = 0; r < 4; ++r) { m_[tl][r] = -1e30f; l_[tl][r] = 0.f; }
  }

  // K staging: chunk idx = it*256+tid; row = idx>>3 (= it*32 + srow), slot = tid&7.
  // Source d-block = slot ^ (row&7)  (it*32 ≡ 0 mod 8 keeps swizzle per-row stable)
  const int srow = tid >> 3, ssp = tid & 7;
  const int ksrc = (ssp ^ (srow & 7)) * 8;
  // V->reg->Vt scatter: per thread kv = vkv0 + {0,32,64,96}, d = vd0..vd0+7
  const int vkv0 = tid >> 3, vd0 = (tid & 7) * 8;
  const float SCL2 = 0.18033688011112042f;  // 0.125 * log2(e)

  const int lastA = p >> 1;
  const int nt = ((31 - p) >> 1) + 1;
  for (int t = 0; t < nt; ++t) {
    const int kvb = t * 128;
    const bool doA = (t <= lastA);
    // stage K tile (Ks reads of prev iter finished at barrier C of prev iter)
#pragma unroll
    for (int it = 0; it < 4; ++it)
      gload_lds16(Kp + (long long)(kvb + it * 32 + srow) * 512 + ksrc,
                  Ks + (it * 256 + tid) * 8);
    // V tile -> regs
    u16x8 vr[4];
#pragma unroll
    for (int j = 0; j < 4; ++j)
      vr[j] = *reinterpret_cast<const u16x8*>(
          Vp + (long long)(kvb + vkv0 + j * 32) * 512 + vd0);
    __syncthreads();  // A: prev PV done -> Vt writable (also drains K stage)
#pragma unroll
    for (int j = 0; j < 4; ++j)
#pragma unroll
      for (int i = 0; i < 8; ++i)
        Vt[(vd0 + i) * 136 + vkv0 + j * 32] = vr[j][i];
    __syncthreads();  // B: Vt + Ks visible

    // S = Q K^T for both tiles (K frags loaded once, shared)
    f32x4 s[2][8];
#pragma unroll
    for (int tl = 0; tl < 2; ++tl)
#pragma unroll
      for (int nf = 0; nf < 8; ++nf) s[tl][nf] = {0.f, 0.f, 0.f, 0.f};
#pragma unroll
    for (int kc = 0; kc < 2; ++kc) {
      bf16x8 kb[8];
#pragma unroll
      for (int nf = 0; nf < 8; ++nf) {
        int kvr = nf * 16 + c;
        int slot = (kc * 4 + g) ^ (kvr & 7);
        kb[nf] = ld_frag(&Ks[kvr * 64 + slot * 8]);
      }
#pragma unroll
      for (int nf = 0; nf < 8; ++nf)
        s[1][nf] = __builtin_amdgcn_mfma_f32_16x16x32_bf16(qa[1][kc], kb[nf], s[1][nf], 0, 0, 0);
      if (doA) {
#pragma unroll
        for (int nf = 0; nf < 8; ++nf)
          s[0][nf] = __builtin_amdgcn_mfma_f32_16x16x32_bf16(qa[0][kc], kb[nf], s[0][nf], 0, 0, 0);
      }
    }
    __syncthreads();  // C: Ks free for next stage

    // per-tile: softmax -> P (wave-private LDS) -> PV, no barriers needed
#pragma unroll
    for (int tl = 0; tl < 2; ++tl) {
      if (tl == 0 && !doA) continue;
      const bool diag = (tl == 0) ? (t == lastA) : (t == nt - 1);
      const int qr0 = qb[tl] + wv * 16 + g * 4;
#pragma unroll
      for (int r = 0; r < 4; ++r) {
        float vmax = -1e30f;
#pragma unroll
        for (int nf = 0; nf < 8; ++nf) {
          float sv = s[tl][nf][r] * SCL2;
          if (diag && (kvb + nf * 16 + c > qr0 + r)) sv = -1e30f;
          s[tl][nf][r] = sv;
          vmax = fmaxf(vmax, sv);
        }
#pragma unroll
        for (int sh = 1; sh < 16; sh <<= 1)
          vmax = fmaxf(vmax, __shfl_xor(vmax, sh, 64));
        float mo = m_[tl][r];
        float mn = fmaxf(mo, vmax);
        float ps = 0.f;
#pragma unroll
        for (int nf = 0; nf < 8; ++nf) {
          float pv = exp2f(s[tl][nf][r] - mn);
          s[tl][nf][r] = pv;
          ps += pv;
        }
#pragma unroll
        for (int sh = 1; sh < 16; sh <<= 1)
          ps += __shfl_xor(ps, sh, 64);
        if (mn > mo) {  // rescale only when running max grew
          float corr = exp2f(mo - mn);
          l_[tl][r] = l_[tl][r] * corr;
#pragma unroll
          for (int nf = 0; nf < 4; ++nf) o[tl][nf][r] *= corr;
          m_[tl][r] = mn;
        }
        l_[tl][r] += ps;
      }
      // P -> LDS (own rows only)
#pragma unroll
      for (int nf = 0; nf < 8; ++nf)
#pragma unroll
        for (int r = 0; r < 4; ++r)
          Ps[(wv * 16 + g * 4 + r) * 136 + nf * 16 + c] = f2bf(s[tl][nf][r]);
      // O += P V (reads own Ps rows; Vt stable since barrier B)
#pragma unroll
      for (int kc2 = 0; kc2 < 4; ++kc2) {
        bf16x8 pa = ld_frag(&Ps[(wv * 16 + c) * 136 + kc2 * 32 + g * 8]);
#pragma unroll
        for (int nf = 0; nf < 4; ++nf) {
          bf16x8 vb = ld_frag(&Vt[(nf * 16 + c) * 136 + kc2 * 32 + g * 8]);
          o[tl][nf] = __builtin_amdgcn_mfma_f32_16x16x32_bf16(pa, vb, o[tl][nf], 0, 0, 0);
        }
      }
    }
  }

  // normalize + store both tiles
#pragma unroll
  for (int tl = 0; tl < 2; ++tl) {
#pragma unroll
    for (int r = 0; r < 4; ++r) {
      float inv = 1.0f / l_[tl][r];
      long long row = rowB + qb[tl] + wv * 16 + g * 4 + r;
#pragma unroll
      for (int nf = 0; nf < 4; ++nf)
        O[row * 512 + h * 64 + nf * 16 + c] = f2bf(o[tl][nf][r] * inv);
    }
  }
}

// ---------------------------------------------------------------- launcher
extern "C" void kernel_launch(void* const* d_in, const int* in_sizes, int n_in,
                              void* d_out, int out_size, void* d_ws, size_t ws_size,
                              hipStream_t stream) {
  const float* x = (const float*)d_in[0];
  const float* CQ_w = (const float*)d_in[1];   const float* CQ_b = (const float*)d_in[2];
  const float* CQC_w = (const float*)d_in[3];  const float* CQC_b = (const float*)d_in[4];
  const float* CQR_w = (const float*)d_in[5];  const float* CQR_b = (const float*)d_in[6];
  const float* CKV_w = (const float*)d_in[7];  const float* CKV_b = (const float*)d_in[8];
  const float* CKR_w = (const float*)d_in[9];  const float* CKR_b = (const float*)d_in[10];
  const float* CKC_w = (const float*)d_in[11]; const float* CKC_b = (const float*)d_in[12];
  const float* CV_w = (const float*)d_in[13];  const float* CV_b = (const float*)d_in[14];
  const float* OUT_w = (const float*)d_in[15]; const float* OUT_b = (const float*)d_in[16];
  float* out = (float*)d_out;

  char* ws = (char*)d_ws;
  size_t off = 0;
  auto alloc = [&](size_t bytes) -> void* {
    void* pp = ws + off;
    off += (bytes + 255) & ~(size_t)255;
    return pp;
  };
  u16* xb   = (u16*)alloc(8192ULL * 2048 * 2);
  u16* Wc1  = (u16*)alloc(1280ULL * 2048 * 2);
  u16* Wcqc = (u16*)alloc(384ULL * 512 * 2);
  u16* Wc2  = (u16*)alloc(896ULL * 512 * 2);
  u16* Wout = (u16*)alloc(2048ULL * 512 * 2);
  u16* cq   = (u16*)alloc(8192ULL * 512 * 2);
  u16* ckv  = (u16*)alloc(8192ULL * 512 * 2);
  u16* cqrt = (u16*)alloc(8192ULL * 128 * 2);
  u16* ckrt = (u16*)alloc(8192ULL * 128 * 2);
  u16* Qb   = (u16*)alloc(8192ULL * 512 * 2);
  u16* Kbf  = (u16*)alloc(8192ULL * 512 * 2);
  u16* Vb   = (u16*)alloc(8192ULL * 512 * 2);
  u16* AO   = (u16*)alloc(8192ULL * 512 * 2);
  (void)ws_size; (void)in_sizes; (void)n_in; (void)out_size;

  conv_f32_bf16<<<2048, 256, 0, stream>>>(x, xb, 8192 * 2048 / 4);

  ConvTab ct;
  ct.src[0] = CQ_w;  ct.dst[0] = Wc1;
  ct.src[1] = CKV_w; ct.dst[1] = Wc1 + 512 * 2048;
  ct.src[2] = CQR_w; ct.dst[2] = Wc1 + 1024 * 2048;
  ct.src[3] = CKR_w; ct.dst[3] = Wc1 + 1152 * 2048;
  ct.src[4] = CQC_w; ct.dst[4] = Wcqc;
  ct.src[5] = CKC_w; ct.dst[5] = Wc2;
  ct.src[6] = CV_w;  ct.dst[6] = Wc2 + 384 * 512;
  ct.src[7] = OUT_w; ct.dst[7] = Wout;
  int bs = 0;
  int nblk[8] = {256, 256, 64, 64, 48, 48, 64, 256};
  for (int i = 0; i < 8; ++i) { ct.bstart[i] = bs; bs += nblk[i]; }
  conv_w_fused<<<bs, 256, 0, stream>>>(ct);

  EpiTable t1 = {};
  t1.nseg = 4;
  t1.s[0] = { CQ_b,  cq,   512, 0,    1 };
  t1.s[1] = { CKV_b, ckv,  512, 512,  1 };
  t1.s[2] = { CQR_b, cqrt, 128, 1024, 0 };
  t1.s[3] = { CKR_b, ckrt, 128, 1152, 0 };
  gemm_bt<0><<<dim3(64, 10), 256, 0, stream>>>(xb, Wc1, 2048, t1);

  rope_gelu_k<<<dim3(8192 * 64 / 256), 256, 0, stream>>>(cqrt, ckrt, Qb, Kbf);

  EpiTable t2 = {};
  t2.nseg = 1;
  t2.s[0] = { CQC_b, Qb, 512, 0, 1 };
  gemm_bt<0><<<dim3(64, 3), 256, 0, stream>>>(cq, Wcqc, 512, t2);

  EpiTable t3 = {};
  t3.nseg = 2;
  t3.s[0] = { CKC_b, Kbf, 512, 0, 1 };
  t3.s[1] = { CV_b,  Vb,  512, 384, 0 };
  gemm_bt<0><<<dim3(64, 7), 256, 0, stream>>>(ckv, Wc2, 512, t3);

  attn_fwd<<<dim3(16, 32), 256, 0, stream>>>(Qb, Kbf, Vb, AO);

  EpiTable t4 = {};
  t4.nseg = 1;
  t4.s[0] = { OUT_b, out, 2048, 0, 0 };
  gemm_bt<1><<<dim3(64, 16), 256, 0, stream>>>(AO, Wout, 512, t4);
}

// Round 10
// 470.023 us; speedup vs baseline: 1.0620x; 1.0620x over previous
//
#include <hip/hip_runtime.h>
#include <cstdint>
#include <cstddef>

typedef unsigned short u16;
typedef short bf16x8 __attribute__((ext_vector_type(8)));
typedef float f32x4 __attribute__((ext_vector_type(4)));
typedef unsigned short u16x8 __attribute__((ext_vector_type(8)));

#define DEVINL __device__ __forceinline__

DEVINL u16 f2bf(float f) {
  union { float f; unsigned u; } v; v.f = f;
  unsigned r = v.u + 0x7FFFu + ((v.u >> 16) & 1u);
  return (u16)(r >> 16);
}
DEVINL float bf2f(u16 h) {
  union { unsigned u; float f; } v; v.u = ((unsigned)h) << 16;
  return v.f;
}
DEVINL float gelu_exact(float x) {
  return 0.5f * x * (1.0f + erff(x * 0.70710678118654752f));
}
DEVINL void gload_lds16(const void* g, void* l) {
  __builtin_amdgcn_global_load_lds(
      (const __attribute__((address_space(1))) void*)g,
      (__attribute__((address_space(3))) void*)l, 16, 0, 0);
}
DEVINL bf16x8 ld_frag(const u16* p) {
  return *reinterpret_cast<const bf16x8*>(p);
}

// ---------------------------------------------------------------- convert x
__global__ __launch_bounds__(256) void conv_f32_bf16(
    const float* __restrict__ src, u16* __restrict__ dst, int n4) {
  int i = blockIdx.x * 256 + threadIdx.x;
  int stride = gridDim.x * 256;
  for (; i < n4; i += stride) {
    float4 v = reinterpret_cast<const float4*>(src)[i];
    ushort4 o;
    o.x = f2bf(v.x); o.y = f2bf(v.y); o.z = f2bf(v.z); o.w = f2bf(v.w);
    reinterpret_cast<ushort4*>(dst)[i] = o;
  }
}

// ------------------------------------------------- fused weight converts
struct ConvTab {
  const float* src[8];
  u16* dst[8];
  int bstart[8];
};
__global__ __launch_bounds__(256) void conv_w_fused(ConvTab t) {
  int blk = blockIdx.x;
  int seg = 0;
#pragma unroll
  for (int i = 1; i < 8; ++i)
    if (blk >= t.bstart[i]) seg = i;
  const float* src = t.src[seg];
  u16* dst = t.dst[seg];
  int base = (blk - t.bstart[seg]) * 1024 + threadIdx.x;
#pragma unroll
  for (int k = 0; k < 4; ++k) {
    int i = base + k * 256;
    float4 v = reinterpret_cast<const float4*>(src)[i];
    ushort4 o;
    o.x = f2bf(v.x); o.y = f2bf(v.y); o.z = f2bf(v.z); o.w = f2bf(v.w);
    reinterpret_cast<ushort4*>(dst)[i] = o;
  }
}

// ---------------------------------------------------------------- GEMM (B^T)
struct EpiSeg {
  const float* bias;
  void* dst;
  int stride;
  int col_start;
  int do_gelu;
};
struct EpiTable { EpiSeg s[4]; int nseg; };

template <int F32OUT>
__global__ __launch_bounds__(256) void gemm_bt(
    const u16* __restrict__ A, const u16* __restrict__ W, int K, EpiTable et) {
  __shared__ u16 As[128 * 32];
  __shared__ u16 Bs[128 * 32];
  const int tid = threadIdx.x;
  const int lane = tid & 63;
  const int wv = tid >> 6;
  const int g = lane >> 4;
  const int c = lane & 15;
  const int wr = (wv >> 1) * 64;
  const int wc = (wv & 1) * 64;

  int bx = blockIdx.x, by = blockIdx.y;
  {
    int nwg = gridDim.x * gridDim.y;
    if ((nwg & 7) == 0) {
      int lid = by * gridDim.x + bx;
      int qq = nwg >> 3;
      int swz = (lid & 7) * qq + (lid >> 3);
      bx = swz % gridDim.x;
      by = swz / gridDim.x;
    }
  }
  const long long rowBase = (long long)bx * 128;
  const long long colBase = (long long)by * 128;

  f32x4 acc[4][4];
#pragma unroll
  for (int m = 0; m < 4; ++m)
#pragma unroll
    for (int n = 0; n < 4; ++n) acc[m][n] = {0.f, 0.f, 0.f, 0.f};

  const int r0 = tid >> 2, sp0 = tid & 3;
  const int scol = (sp0 ^ ((r0 >> 1) & 3)) * 8;
  const u16* Ag = A + (rowBase + r0) * K + scol;
  const u16* Wg = W + (colBase + r0) * K + scol;
  u16* Al0 = As + tid * 8;
  u16* Al1 = As + (256 + tid) * 8;
  u16* Bl0 = Bs + tid * 8;
  u16* Bl1 = Bs + (256 + tid) * 8;
  const long long skip = 64LL * K;

  int aoff[4], boff[4];
#pragma unroll
  for (int m = 0; m < 4; ++m) {
    int row = wr + m * 16 + c;
    aoff[m] = row * 32 + ((g ^ ((row >> 1) & 3)) * 8);
    int rowb = wc + m * 16 + c;
    boff[m] = rowb * 32 + ((g ^ ((rowb >> 1) & 3)) * 8);
  }

  const int nk = K >> 5;
  for (int kt = 0; kt < nk; ++kt) {
    const int k0 = kt * 32;
    gload_lds16(Ag + k0, Al0);
    gload_lds16(Ag + skip + k0, Al1);
    gload_lds16(Wg + k0, Bl0);
    gload_lds16(Wg + skip + k0, Bl1);
    __syncthreads();
    bf16x8 a[4], b[4];
#pragma unroll
    for (int m = 0; m < 4; ++m) a[m] = ld_frag(&As[aoff[m]]);
#pragma unroll
    for (int n = 0; n < 4; ++n) b[n] = ld_frag(&Bs[boff[n]]);
#pragma unroll
    for (int m = 0; m < 4; ++m)
#pragma unroll
      for (int n = 0; n < 4; ++n)
        acc[m][n] = __builtin_amdgcn_mfma_f32_16x16x32_bf16(a[m], b[n], acc[m][n], 0, 0, 0);
    __syncthreads();
  }

  EpiSeg e = et.s[0];
#pragma unroll
  for (int i = 1; i < 4; ++i)
    if (i < et.nseg && (int)colBase >= et.s[i].col_start) e = et.s[i];

#pragma unroll
  for (int m = 0; m < 4; ++m) {
#pragma unroll
    for (int n = 0; n < 4; ++n) {
      int col = (int)colBase + wc + n * 16 + c;
      int dcol = col - e.col_start;
      float bias = e.bias[dcol];
#pragma unroll
      for (int r = 0; r < 4; ++r) {
        long long row = rowBase + wr + m * 16 + g * 4 + r;
        float v = acc[m][n][r] + bias;
        if (e.do_gelu) v = gelu_exact(v);
        if (F32OUT)
          ((float*)e.dst)[row * e.stride + dcol] = v;
        else
          ((u16*)e.dst)[row * e.stride + dcol] = f2bf(v);
      }
    }
  }
}

// ---------------------------------------------------------------- RoPE + gelu
__global__ __launch_bounds__(256) void rope_gelu_k(
    const u16* __restrict__ cqr, const u16* __restrict__ ckr,
    u16* __restrict__ Qb, u16* __restrict__ Kb) {
  int idx = blockIdx.x * 256 + threadIdx.x;
  int row = idx >> 6, j = idx & 63;
  int s = row & 2047;
  float invf = exp2f(-(float)j * (13.287712379549449f / 64.f));
  float th = (float)s * invf;
  float sn, cs;
  sincosf(th, &sn, &cs);
  long long r128 = (long long)row * 128;
  float q1 = bf2f(cqr[r128 + j]), q2 = bf2f(cqr[r128 + 64 + j]);
  float k1 = bf2f(ckr[r128 + j]), k2 = bf2f(ckr[r128 + 64 + j]);
  float qo1 = q1 * cs - q2 * sn, qo2 = q2 * cs + q1 * sn;
  float ko1 = k1 * cs - k2 * sn, ko2 = k2 * cs + k1 * sn;
  long long rb = (long long)row * 512;
  Qb[rb + 384 + j] = f2bf(gelu_exact(qo1));
  Qb[rb + 448 + j] = f2bf(gelu_exact(qo2));
  Kb[rb + 384 + j] = f2bf(gelu_exact(ko1));
  Kb[rb + 448 + j] = f2bf(gelu_exact(ko2));
}

// ---------------------------------------------------------------- attention
// Diagonal-paired causal flash attention. R7 per-wave structure (KVB=64),
// split into 2-wave blocks for 2x grid parallelism:
//   block (p, bh): q-tiles p and 63-p, 32 rows each; wave wv owns rows
//   [qb + wv*16, +16) of each tile. Grid 32x32 = 1024 blocks = 4/CU.
//   Work per block = exactly 33 tile-units of 64 kv for every p.
// Barriers: 3 per 64-kv iteration; Ps rows are wave-private (no barrier
// between P-write and PV).
__global__ __launch_bounds__(128) void attn_fwd(
    const u16* __restrict__ Q, const u16* __restrict__ Kin,
    const u16* __restrict__ V, u16* __restrict__ O) {
  const int p = blockIdx.x;        // pair id 0..31
  const int bh = blockIdx.y;
  const int b = bh >> 3, h = bh & 7;
  const int tid = threadIdx.x, lane = tid & 63, wv = tid >> 6;  // wv in {0,1}
  const int g = lane >> 4, c = lane & 15;

  __shared__ u16 Ks[64 * 64];      // [kv][d-slot swizzled]   8.0 KB
  __shared__ u16 Vt[64 * 72];      // [d][kv] transposed, pad 9.2 KB
  __shared__ u16 Ps[64 * 72];      // rows: tl*32 + wv*16 + r 9.2 KB

  const long long rowB = (long long)b * 2048;
  const int qb[2] = { p * 32, (63 - p) * 32 };
  const u16* Kp = Kin + rowB * 512 + h * 64;
  const u16* Vp = V + rowB * 512 + h * 64;

  // Q fragments (A-operand: lane holds Q[row=c][k=g*8..+7])
  bf16x8 qa[2][2];
#pragma unroll
  for (int tl = 0; tl < 2; ++tl) {
    const u16* Qp = Q + (rowB + qb[tl] + wv * 16 + c) * 512 + h * 64;
#pragma unroll
    for (int kc = 0; kc < 2; ++kc)
      qa[tl][kc] = ld_frag(Qp + kc * 32 + g * 8);
  }

  f32x4 o[2][4];
  float m_[2][4], l_[2][4];
#pragma unroll
  for (int tl = 0; tl < 2; ++tl) {
#pragma unroll
    for (int nf = 0; nf < 4; ++nf) o[tl][nf] = {0.f, 0.f, 0.f, 0.f};
#pragma unroll
    for (int r = 0; r < 4; ++r) { m_[tl][r] = -1e30f; l_[tl][r] = 0.f; }
  }

  // K staging (128 thr, 4 chunks each): chunk = it*128+tid -> row it*16+srow,
  // slot ssp; source d-block = ssp ^ (row&7) (it*16 ≡ 0 mod 8 -> stable)
  const int srow = tid >> 3, ssp = tid & 7;
  const int ksrc = (ssp ^ (srow & 7)) * 8;
  // V scatter: thread covers kv = vkv0+{0,16,32,48}, d = vd0..vd0+7
  const int vkv0 = tid >> 3, vd0 = (tid & 7) * 8;
  const float SCL2 = 0.18033688011112042f;  // 0.125 * log2(e)

  const int lastA = p >> 1;
  const int nt = 32 - (p >> 1);   // tile B last kv-tile index + 1
  for (int t = 0; t < nt; ++t) {
    const int kvb = t * 64;
    const bool doA = (t <= lastA);
    // stage K tile (Ks reads finished at barrier C of prev iter)
#pragma unroll
    for (int it = 0; it < 4; ++it)
      gload_lds16(Kp + (long long)(kvb + it * 16 + srow) * 512 + ksrc,
                  Ks + (it * 128 + tid) * 8);
    // V tile -> regs
    u16x8 vr[4];
#pragma unroll
    for (int j = 0; j < 4; ++j)
      vr[j] = *reinterpret_cast<const u16x8*>(
          Vp + (long long)(kvb + vkv0 + j * 16) * 512 + vd0);
    __syncthreads();  // A: prev PV done -> Vt writable (also drains K stage)
#pragma unroll
    for (int j = 0; j < 4; ++j)
#pragma unroll
      for (int i = 0; i < 8; ++i)
        Vt[(vd0 + i) * 72 + vkv0 + j * 16] = vr[j][i];
    __syncthreads();  // B: Vt + Ks visible

    // S = Q K^T for both tiles (K frags loaded once, shared)
    f32x4 s[2][4];
#pragma unroll
    for (int tl = 0; tl < 2; ++tl)
#pragma unroll
      for (int nf = 0; nf < 4; ++nf) s[tl][nf] = {0.f, 0.f, 0.f, 0.f};
#pragma unroll
    for (int kc = 0; kc < 2; ++kc) {
      bf16x8 kb[4];
#pragma unroll
      for (int nf = 0; nf < 4; ++nf) {
        int kvr = nf * 16 + c;
        int slot = (kc * 4 + g) ^ (kvr & 7);
        kb[nf] = ld_frag(&Ks[kvr * 64 + slot * 8]);
      }
#pragma unroll
      for (int nf = 0; nf < 4; ++nf)
        s[1][nf] = __builtin_amdgcn_mfma_f32_16x16x32_bf16(qa[1][kc], kb[nf], s[1][nf], 0, 0, 0);
      if (doA) {
#pragma unroll
        for (int nf = 0; nf < 4; ++nf)
          s[0][nf] = __builtin_amdgcn_mfma_f32_16x16x32_bf16(qa[0][kc], kb[nf], s[0][nf], 0, 0, 0);
      }
    }
    __syncthreads();  // C: Ks free for next stage

    // per-tile: softmax -> P (wave-private rows) -> PV
#pragma unroll
    for (int tl = 0; tl < 2; ++tl) {
      if (tl == 0 && !doA) continue;
      const bool diag = (tl == 0) ? (t == lastA) : (t == nt - 1);
      const int qr0 = qb[tl] + wv * 16 + g * 4;
      const int prow = tl * 32 + wv * 16;
#pragma unroll
      for (int r = 0; r < 4; ++r) {
        float vmax = -1e30f;
#pragma unroll
        for (int nf = 0; nf < 4; ++nf) {
          float sv = s[tl][nf][r] * SCL2;
          if (diag && (kvb + nf * 16 + c > qr0 + r)) sv = -1e30f;
          s[tl][nf][r] = sv;
          vmax = fmaxf(vmax, sv);
        }
#pragma unroll
        for (int sh = 1; sh < 16; sh <<= 1)
          vmax = fmaxf(vmax, __shfl_xor(vmax, sh, 64));
        float mo = m_[tl][r];
        float mn = fmaxf(mo, vmax);
        float corr = exp2f(mo - mn);
        float ps = 0.f;
#pragma unroll
        for (int nf = 0; nf < 4; ++nf) {
          float pv = exp2f(s[tl][nf][r] - mn);
          s[tl][nf][r] = pv;
          ps += pv;
        }
#pragma unroll
        for (int sh = 1; sh < 16; sh <<= 1)
          ps += __shfl_xor(ps, sh, 64);
        m_[tl][r] = mn;
        l_[tl][r] = l_[tl][r] * corr + ps;
#pragma unroll
        for (int nf = 0; nf < 4; ++nf) o[tl][nf][r] *= corr;
      }
      // P -> LDS (own rows only)
#pragma unroll
      for (int nf = 0; nf < 4; ++nf)
#pragma unroll
        for (int r = 0; r < 4; ++r)
          Ps[(prow + g * 4 + r) * 72 + nf * 16 + c] = f2bf(s[tl][nf][r]);
      // O += P V (reads own Ps rows; Vt stable since barrier B)
#pragma unroll
      for (int kc2 = 0; kc2 < 2; ++kc2) {
        bf16x8 pa = ld_frag(&Ps[(prow + c) * 72 + kc2 * 32 + g * 8]);
#pragma unroll
        for (int nf = 0; nf < 4; ++nf) {
          bf16x8 vb = ld_frag(&Vt[(nf * 16 + c) * 72 + kc2 * 32 + g * 8]);
          o[tl][nf] = __builtin_amdgcn_mfma_f32_16x16x32_bf16(pa, vb, o[tl][nf], 0, 0, 0);
        }
      }
    }
  }

  // normalize + store both tiles
#pragma unroll
  for (int tl = 0; tl < 2; ++tl) {
#pragma unroll
    for (int r = 0; r < 4; ++r) {
      float inv = 1.0f / l_[tl][r];
      long long row = rowB + qb[tl] + wv * 16 + g * 4 + r;
#pragma unroll
      for (int nf = 0; nf < 4; ++nf)
        O[row * 512 + h * 64 + nf * 16 + c] = f2bf(o[tl][nf][r] * inv);
    }
  }
}

// ---------------------------------------------------------------- launcher
extern "C" void kernel_launch(void* const* d_in, const int* in_sizes, int n_in,
                              void* d_out, int out_size, void* d_ws, size_t ws_size,
                              hipStream_t stream) {
  const float* x = (const float*)d_in[0];
  const float* CQ_w = (const float*)d_in[1];   const float* CQ_b = (const float*)d_in[2];
  const float* CQC_w = (const float*)d_in[3];  const float* CQC_b = (const float*)d_in[4];
  const float* CQR_w = (const float*)d_in[5];  const float* CQR_b = (const float*)d_in[6];
  const float* CKV_w = (const float*)d_in[7];  const float* CKV_b = (const float*)d_in[8];
  const float* CKR_w = (const float*)d_in[9];  const float* CKR_b = (const float*)d_in[10];
  const float* CKC_w = (const float*)d_in[11]; const float* CKC_b = (const float*)d_in[12];
  const float* CV_w = (const float*)d_in[13];  const float* CV_b = (const float*)d_in[14];
  const float* OUT_w = (const float*)d_in[15]; const float* OUT_b = (const float*)d_in[16];
  float* out = (float*)d_out;

  char* ws = (char*)d_ws;
  size_t off = 0;
  auto alloc = [&](size_t bytes) -> void* {
    void* pp = ws + off;
    off += (bytes + 255) & ~(size_t)255;
    return pp;
  };
  u16* xb   = (u16*)alloc(8192ULL * 2048 * 2);
  u16* Wc1  = (u16*)alloc(1280ULL * 2048 * 2);
  u16* Wcqc = (u16*)alloc(384ULL * 512 * 2);
  u16* Wc2  = (u16*)alloc(896ULL * 512 * 2);
  u16* Wout = (u16*)alloc(2048ULL * 512 * 2);
  u16* cq   = (u16*)alloc(8192ULL * 512 * 2);
  u16* ckv  = (u16*)alloc(8192ULL * 512 * 2);
  u16* cqrt = (u16*)alloc(8192ULL * 128 * 2);
  u16* ckrt = (u16*)alloc(8192ULL * 128 * 2);
  u16* Qb   = (u16*)alloc(8192ULL * 512 * 2);
  u16* Kbf  = (u16*)alloc(8192ULL * 512 * 2);
  u16* Vb   = (u16*)alloc(8192ULL * 512 * 2);
  u16* AO   = (u16*)alloc(8192ULL * 512 * 2);
  (void)ws_size; (void)in_sizes; (void)n_in; (void)out_size;

  conv_f32_bf16<<<2048, 256, 0, stream>>>(x, xb, 8192 * 2048 / 4);

  ConvTab ct;
  ct.src[0] = CQ_w;  ct.dst[0] = Wc1;
  ct.src[1] = CKV_w; ct.dst[1] = Wc1 + 512 * 2048;
  ct.src[2] = CQR_w; ct.dst[2] = Wc1 + 1024 * 2048;
  ct.src[3] = CKR_w; ct.dst[3] = Wc1 + 1152 * 2048;
  ct.src[4] = CQC_w; ct.dst[4] = Wcqc;
  ct.src[5] = CKC_w; ct.dst[5] = Wc2;
  ct.src[6] = CV_w;  ct.dst[6] = Wc2 + 384 * 512;
  ct.src[7] = OUT_w; ct.dst[7] = Wout;
  int bs = 0;
  int nblk[8] = {256, 256, 64, 64, 48, 48, 64, 256};
  for (int i = 0; i < 8; ++i) { ct.bstart[i] = bs; bs += nblk[i]; }
  conv_w_fused<<<bs, 256, 0, stream>>>(ct);

  EpiTable t1 = {};
  t1.nseg = 4;
  t1.s[0] = { CQ_b,  cq,   512, 0,    1 };
  t1.s[1] = { CKV_b, ckv,  512, 512,  1 };
  t1.s[2] = { CQR_b, cqrt, 128, 1024, 0 };
  t1.s[3] = { CKR_b, ckrt, 128, 1152, 0 };
  gemm_bt<0><<<dim3(64, 10), 256, 0, stream>>>(xb, Wc1, 2048, t1);

  rope_gelu_k<<<dim3(8192 * 64 / 256), 256, 0, stream>>>(cqrt, ckrt, Qb, Kbf);

  EpiTable t2 = {};
  t2.nseg = 1;
  t2.s[0] = { CQC_b, Qb, 512, 0, 1 };
  gemm_bt<0><<<dim3(64, 3), 256, 0, stream>>>(cq, Wcqc, 512, t2);

  EpiTable t3 = {};
  t3.nseg = 2;
  t3.s[0] = { CKC_b, Kbf, 512, 0, 1 };
  t3.s[1] = { CV_b,  Vb,  512, 384, 0 };
  gemm_bt<0><<<dim3(64, 7), 256, 0, stream>>>(ckv, Wc2, 512, t3);

  attn_fwd<<<dim3(32, 32), 128, 0, stream>>>(Qb, Kbf, Vb, AO);

  EpiTable t4 = {};
  t4.nseg = 1;
  t4.s[0] = { OUT_b, out, 2048, 0, 0 };
  gemm_bt<1><<<dim3(64, 16), 256, 0, stream>>>(AO, Wout, 512, t4);
}